// Round 2
// baseline (1876.189 us; speedup 1.0000x reference)
//
#include <hip/hip_runtime.h>
#include <hip/hip_bf16.h>
#include <math.h>

// Problem constants
#define Hh   128          // hidden size
#define G4H  512          // 4*H
#define Bb   256          // batch
#define Tt   512          // seq len
#define INL0 64           // layer-0 input size

// ---------------- activation helper ----------------
// sigmoid; tanh(x) computed as 2*sigmoid(2x)-1 (branchless, single exp path)
__device__ __forceinline__ float sigmoid_f(float x) {
    return 1.0f / (1.0f + __expf(-x));
}

// ---------------- xg GEMM ----------------
// xg[mc, g] = sum_k A[row(mc), k] * W[g, k] + bih[g] + bhh[g]
// A is [B*T, K] row-major; chunk row mc = b*Tc + tl -> global row b*T + t0 + tl.
// Tile: BM=128 x BN=128, BK=32, 256 threads, 8x8 micro-tile.
#define BM 128
#define BN 128
#define BK 32

__global__ __launch_bounds__(256) void xg_gemm(
    const float* __restrict__ A, const float* __restrict__ W,
    const float* __restrict__ bih, const float* __restrict__ bhh,
    float* __restrict__ xg, int K, int Tc, int t0)
{
    __shared__ float As[BK][BM + 4];
    __shared__ float Bs[BK][BN + 4];

    const int tid = threadIdx.x;
    const int tx  = tid & 15;
    const int ty  = tid >> 4;
    const int mc0 = blockIdx.x * BM;
    const int n0  = blockIdx.y * BN;

    const int la_r = tid >> 3;          // 0..31
    const int la_c = (tid & 7) * 4;     // 0,4,...,28

    const float* aptr[4];
    const float* wptr[4];
#pragma unroll
    for (int p = 0; p < 4; ++p) {
        int rc = mc0 + la_r + p * 32;       // chunk row
        int bb = rc / Tc;
        int tl = rc - bb * Tc;
        aptr[p] = A + (size_t)(bb * Tt + t0 + tl) * K + la_c;
        wptr[p] = W + (size_t)(n0 + la_r + p * 32) * K + la_c;
    }

    float acc[8][8];
#pragma unroll
    for (int i = 0; i < 8; ++i)
#pragma unroll
        for (int j = 0; j < 8; ++j) acc[i][j] = 0.0f;

    for (int k0 = 0; k0 < K; k0 += BK) {
#pragma unroll
        for (int p = 0; p < 4; ++p) {
            float4 av = *(const float4*)(aptr[p] + k0);
            int r = la_r + p * 32;
            As[la_c + 0][r] = av.x;
            As[la_c + 1][r] = av.y;
            As[la_c + 2][r] = av.z;
            As[la_c + 3][r] = av.w;
            float4 wv = *(const float4*)(wptr[p] + k0);
            Bs[la_c + 0][r] = wv.x;
            Bs[la_c + 1][r] = wv.y;
            Bs[la_c + 2][r] = wv.z;
            Bs[la_c + 3][r] = wv.w;
        }
        __syncthreads();

#pragma unroll 8
        for (int k = 0; k < BK; ++k) {
            float4 a0 = *(const float4*)&As[k][ty * 8];
            float4 a1 = *(const float4*)&As[k][ty * 8 + 4];
            float4 b0 = *(const float4*)&Bs[k][tx * 8];
            float4 b1 = *(const float4*)&Bs[k][tx * 8 + 4];
            float av[8] = {a0.x, a0.y, a0.z, a0.w, a1.x, a1.y, a1.z, a1.w};
            float bv[8] = {b0.x, b0.y, b0.z, b0.w, b1.x, b1.y, b1.z, b1.w};
#pragma unroll
            for (int i = 0; i < 8; ++i)
#pragma unroll
                for (int j = 0; j < 8; ++j)
                    acc[i][j] = fmaf(av[i], bv[j], acc[i][j]);
        }
        __syncthreads();
    }

    const int row0 = mc0 + ty * 8;
    const int col0 = n0 + tx * 8;
    float bias[8];
#pragma unroll
    for (int j = 0; j < 8; ++j) bias[j] = bih[col0 + j] + bhh[col0 + j];
#pragma unroll
    for (int i = 0; i < 8; ++i) {
        float4 v0 = {acc[i][0] + bias[0], acc[i][1] + bias[1],
                     acc[i][2] + bias[2], acc[i][3] + bias[3]};
        float4 v1 = {acc[i][4] + bias[4], acc[i][5] + bias[5],
                     acc[i][6] + bias[6], acc[i][7] + bias[7]};
        float* dst = xg + (size_t)(row0 + i) * G4H + col0;
        *(float4*)(dst)     = v0;
        *(float4*)(dst + 4) = v1;
    }
}

// ---------------- recurrent kernel ----------------
// One block per batch row.  512 threads = 8 waves.
// Thread mapping: wave w = tid>>6, lane = tid&63.
//   unit u = w*16 + (lane&15)   (hidden index, 0..127)
//   gate g = lane>>4            (0:i 1:f 2:g 3:o)
//   Whh row r = g*128 + u.
// All 4 gates of unit u live in ONE wave -> gather via __shfl (no LDS trip).
// h double-buffered in LDS -> exactly ONE barrier per timestep.
__global__ __launch_bounds__(512, 2) void lstm_recur(
    const float* __restrict__ xg,    // [B, Tc, 4H] chunk
    const float* __restrict__ Whh,   // [4H, H]
    float* __restrict__ out,         // [B, T, H] layer output base
    float* __restrict__ h_state, float* __restrict__ c_state,
    int Tc, int t0, int first_chunk,
    float* __restrict__ hn_dst, float* __restrict__ cn_dst,
    float* __restrict__ htop_dst)
{
    __shared__ float hs[2][Hh];

    const int b    = blockIdx.x;
    const int tid  = threadIdx.x;
    const int lane = tid & 63;
    const int u    = (tid >> 6) * 16 + (lane & 15);
    const int g    = (lane >> 4) & 3;
    const int r    = g * Hh + u;
    const bool is_i = (g == 0);      // lane owns the c/h update for unit u

    // persistent weights: Whh row r (128 floats = 32 float4 in VGPRs)
    float4 w[32];
#pragma unroll
    for (int i = 0; i < 32; ++i)
        w[i] = *(const float4*)&Whh[(size_t)r * Hh + i * 4];

    float c = 0.0f, hlast = 0.0f;
    if (is_i) {
        float h0 = 0.0f;
        if (!first_chunk) {
            h0 = h_state[b * Hh + u];
            c  = c_state[b * Hh + u];
        }
        hs[0][u] = h0;
    }
    __syncthreads();

    const float* xgrow = xg + (size_t)b * Tc * G4H + r;
    float cur = xgrow[0];

    for (int s = 0; s < Tc; ++s) {
        const int p = s & 1;
        // prefetch next step's xg under the dot product
        float nxt = 0.0f;
        if (s + 1 < Tc) nxt = xgrow[(size_t)(s + 1) * G4H];

        float a0 = 0.f, a1 = 0.f, a2 = 0.f, a3 = 0.f;
#pragma unroll
        for (int i = 0; i < 32; ++i) {
            float4 hv = *(const float4*)&hs[p][i * 4];   // uniform addr -> broadcast
            a0 = fmaf(w[i].x, hv.x, a0);
            a1 = fmaf(w[i].y, hv.y, a1);
            a2 = fmaf(w[i].z, hv.z, a2);
            a3 = fmaf(w[i].w, hv.w, a3);
        }
        float pre = cur + ((a0 + a1) + (a2 + a3));

        // branchless activation: g-gate uses tanh(x) = 2*sigmoid(2x)-1
        float px  = (g == 2) ? 2.0f * pre : pre;
        float sg  = sigmoid_f(px);
        float act = (g == 2) ? 2.0f * sg - 1.0f : sg;

        // gather f,g,o into the i-lane of each unit (all in-wave)
        int baselane = lane & 15;
        float fv = __shfl(act, baselane + 16);
        float gv = __shfl(act, baselane + 32);
        float ov = __shfl(act, baselane + 48);

        if (is_i) {
            c = fmaf(fv, c, act * gv);                   // act == i-gate here
            float th = 2.0f * sigmoid_f(2.0f * c) - 1.0f;  // tanh(c)
            float h  = ov * th;
            hlast = h;
            hs[p ^ 1][u] = h;
            out[((size_t)b * Tt + t0 + s) * Hh + u] = h;
        }
        __syncthreads();   // writes to hs[p^1] visible; also fences next write to hs[p]
        cur = nxt;
    }

    if (is_i) {
        h_state[b * Hh + u] = hlast;
        c_state[b * Hh + u] = c;
        if (hn_dst) {
            hn_dst[b * Hh + u] = hlast;
            cn_dst[b * Hh + u] = c;
            if (htop_dst) htop_dst[b * Hh + u] = hlast;
        }
    }
}

// ---------------- host launch ----------------
extern "C" void kernel_launch(void* const* d_in, const int* in_sizes, int n_in,
                              void* d_out, int out_size, void* d_ws, size_t ws_size,
                              hipStream_t stream)
{
    const float* x = (const float*)d_in[0];
    const float* Wih[3] = {(const float*)d_in[1], (const float*)d_in[5], (const float*)d_in[9]};
    const float* Whh[3] = {(const float*)d_in[2], (const float*)d_in[6], (const float*)d_in[10]};
    const float* bih[3] = {(const float*)d_in[3], (const float*)d_in[7], (const float*)d_in[11]};
    const float* bhh[3] = {(const float*)d_in[4], (const float*)d_in[8], (const float*)d_in[12]};

    // d_out layout: out[B,T,H] | h_top[B,H] | h_n[3,B,H] | c_n[3,B,H]
    float* out_final = (float*)d_out;
    const size_t OUT_ELEMS = (size_t)Bb * Tt * Hh;       // 16,777,216
    float* htop = out_final + OUT_ELEMS;
    float* hn   = htop + (size_t)Bb * Hh;
    float* cn   = hn + (size_t)3 * Bb * Hh;

    // workspace: h_state | c_state | xg_chunk   (all layers run in-place on out_final)
    float* ws      = (float*)d_ws;
    float* h_state = ws;
    float* c_state = h_state + (size_t)Bb * Hh;
    float* xgbuf   = c_state + (size_t)Bb * Hh;

    // adaptive chunk size so xg fits in workspace
    size_t base_bytes = 2 * (size_t)Bb * Hh * sizeof(float);
    int Tc = Tt;
    while (Tc > 32 &&
           base_bytes + (size_t)Bb * Tc * G4H * sizeof(float) > ws_size)
        Tc >>= 1;

    for (int layer = 0; layer < 3; ++layer) {
        const float* in_ptr = (layer == 0) ? x : out_final;
        const int    K      = (layer == 0) ? INL0 : Hh;
        // In-place is safe per chunk: the GEMM for rows [t0,t0+Tc) completes
        // (stream order) before the recurrence overwrites exactly those rows,
        // and later chunks read rows the recurrence hasn't touched yet.

        for (int t0 = 0; t0 < Tt; t0 += Tc) {
            dim3 ggrid((Bb * Tc) / BM, G4H / BN);
            xg_gemm<<<ggrid, 256, 0, stream>>>(
                in_ptr, Wih[layer], bih[layer], bhh[layer], xgbuf, K, Tc, t0);

            bool last = (t0 + Tc >= Tt);
            lstm_recur<<<Bb, 512, 0, stream>>>(
                xgbuf, Whh[layer], out_final, h_state, c_state,
                Tc, t0, (t0 == 0) ? 1 : 0,
                last ? (hn + (size_t)layer * Bb * Hh) : nullptr,
                last ? (cn + (size_t)layer * Bb * Hh) : nullptr,
                (last && layer == 2) ? htop : nullptr);
        }
    }
}